// Round 2
// baseline (168.991 us; speedup 1.0000x reference)
//
#include <hip/hip_runtime.h>
#include <hip/hip_bf16.h>
#include <math.h>

// B=64, C=3, H=W=512.
// out[b,0] = sigmoid( sum_{c,h,w} x[b,c,h,w] * M_col[h,w] / C )
// out[b,1] = sigmoid( sum_{c,h,w} x[b,c,h,w] * M_row[h,w] / C )
// M_row = (1/HW) D^T (diag(rw) A) D ;  M_col = (1/HW) D^T (A diag(cw)) D

typedef __attribute__((ext_vector_type(8))) short bf16x8;
typedef __attribute__((ext_vector_type(4))) float f32x4;

#define NFULL 512
#define HWTOT 262144
#define SCALE_M (1.0f / 786432.0f)      // 1/(H*W*C)
#define KC_BLOCKS 512

static __device__ __forceinline__ unsigned short f_to_bf16(float f) {
  union { float f; unsigned int i; } v; v.f = f;
  unsigned int r = v.i + 0x7FFFu + ((v.i >> 16) & 1u);   // round-nearest-even
  return (unsigned short)(r >> 16);
}

// ---------------- K0: trig table + scaled bf16 casts + counter reset ----------------
// DT[n][k] = s_k * cos(pi*(n+0.5)*k/512)   (row n = spatial, col k = freq)
// Arw[r][c] = A[r,c]*rw[r] ; Acw[r][c] = A[r,c]*cw[c]
__global__ void k0_prep(const float* __restrict__ att,
                        const float* __restrict__ rw,
                        const float* __restrict__ cw,
                        unsigned short* __restrict__ DT,
                        unsigned short* __restrict__ Arw,
                        unsigned short* __restrict__ Acw,
                        int* __restrict__ counter) {
  int idx = blockIdx.x * blockDim.x + threadIdx.x;   // 0..262143
  int r = idx >> 9;
  int c = idx & 511;
  unsigned int ph = ((unsigned int)(2 * r + 1) * (unsigned int)c) & 2047u;  // period 2048
  float s = (c == 0) ? 0.04419417382415922f   // sqrt(1/512)
                     : 0.0625f;               // sqrt(2/512)
  DT[idx] = f_to_bf16(s * cospif((float)ph * (1.0f / 1024.0f)));
  float a = att[idx];
  Arw[idx] = f_to_bf16(a * rw[r]);
  Acw[idx] = f_to_bf16(a * cw[c]);
  if (idx == 0) *counter = 0;
}

// ---------------- kM: both 512x512x512 GEMM chains in ONE kernel ----------------
// 32 blocks; block owns 16-col strip [w0, w0+16).
// Stage 1: T[m][k, wl] = sum_l P_m[k,l] * DT[w0+wl, l]  -> LDS transposed bf16 (stride 520)
// Stage 2: M_m[h, w0+wl] = sum_k DT[h, k] * T[m][wl, k]
__global__ __launch_bounds__(256) void kM(const unsigned short* __restrict__ DT,
                                          const unsigned short* __restrict__ Arw,
                                          const unsigned short* __restrict__ Acw,
                                          float* __restrict__ Mrow,
                                          float* __restrict__ Mcol) {
  __shared__ unsigned short Tsh[2][16 * 520];   // 2 x 16.25KB, stride 520 -> 2-way banks only
  int w0 = blockIdx.x * 16;
  int tid = threadIdx.x;
  int lane = tid & 63, wv = tid >> 6;
  int l16 = lane & 15;
  int koff8 = (lane >> 4) * 8;
  int r4 = (lane >> 4) * 4;

  const bf16x8* Bp = (const bf16x8*)(DT + (w0 + l16) * NFULL);

  // stage 1: 32 k-tiles split 8/wave, both matrices share the B fragment
  for (int t = 0; t < 8; ++t) {
    int kt = wv * 8 + t;
    const bf16x8* A1 = (const bf16x8*)(Arw + (kt * 16 + l16) * NFULL);
    const bf16x8* A2 = (const bf16x8*)(Acw + (kt * 16 + l16) * NFULL);
    f32x4 acc1 = {0.f, 0.f, 0.f, 0.f};
    f32x4 acc2 = {0.f, 0.f, 0.f, 0.f};
#pragma unroll 4
    for (int l0 = 0; l0 < NFULL; l0 += 32) {
      int e = (l0 + koff8) >> 3;
      bf16x8 b = Bp[e];
      acc1 = __builtin_amdgcn_mfma_f32_16x16x32_bf16(A1[e], b, acc1, 0, 0, 0);
      acc2 = __builtin_amdgcn_mfma_f32_16x16x32_bf16(A2[e], b, acc2, 0, 0, 0);
    }
    // C/D: col = lane&15 (w_local), rows kt*16 + r4 + j  -> store transposed
    int k0 = kt * 16 + r4;
    unsigned int p10 = f_to_bf16(acc1[0]) | ((unsigned int)f_to_bf16(acc1[1]) << 16);
    unsigned int p11 = f_to_bf16(acc1[2]) | ((unsigned int)f_to_bf16(acc1[3]) << 16);
    unsigned int p20 = f_to_bf16(acc2[0]) | ((unsigned int)f_to_bf16(acc2[1]) << 16);
    unsigned int p21 = f_to_bf16(acc2[2]) | ((unsigned int)f_to_bf16(acc2[3]) << 16);
    *(uint2*)&Tsh[0][l16 * 520 + k0] = make_uint2(p10, p11);
    *(uint2*)&Tsh[1][l16 * 520 + k0] = make_uint2(p20, p21);
  }
  __syncthreads();

  // stage 2: 32 h-tiles split 8/wave
  for (int t = 0; t < 8; ++t) {
    int ht = wv * 8 + t;
    const bf16x8* Ap = (const bf16x8*)(DT + (ht * 16 + l16) * NFULL);
    f32x4 aR = {0.f, 0.f, 0.f, 0.f};
    f32x4 aC = {0.f, 0.f, 0.f, 0.f};
#pragma unroll 4
    for (int k0s = 0; k0s < NFULL; k0s += 32) {
      int e = (k0s + koff8) >> 3;
      bf16x8 a = Ap[e];
      bf16x8 b1 = *(const bf16x8*)&Tsh[0][l16 * 520 + k0s + koff8];
      bf16x8 b2 = *(const bf16x8*)&Tsh[1][l16 * 520 + k0s + koff8];
      aR = __builtin_amdgcn_mfma_f32_16x16x32_bf16(a, b1, aR, 0, 0, 0);
      aC = __builtin_amdgcn_mfma_f32_16x16x32_bf16(a, b2, aC, 0, 0, 0);
    }
    int h0 = ht * 16 + r4, w = w0 + l16;
#pragma unroll
    for (int j = 0; j < 4; ++j) {
      Mrow[(h0 + j) * NFULL + w] = aR[j] * SCALE_M;
      Mcol[(h0 + j) * NFULL + w] = aC[j] * SCALE_M;
    }
  }
}

// ---------------- kc: stream x once; M held in registers, reused across 8 batches ----
// grid = 64 hw-slices x 8 batch-groups. Fused last-block final reduce + sigmoid.
__global__ __launch_bounds__(256) void kc_dot(const float* __restrict__ x,
                                              const float* __restrict__ Mcol,
                                              const float* __restrict__ Mrow,
                                              float* __restrict__ partial,
                                              int* __restrict__ counter,
                                              float* __restrict__ out) {
  int sub = blockIdx.x & 63;
  int bg  = blockIdx.x >> 6;
  int tid = threadIdx.x;
  int base = sub * 1024 + tid;

  const f32x4* mc = (const f32x4*)Mcol;
  const f32x4* mr = (const f32x4*)Mrow;
  f32x4 mcr[4], mrr[4];
#pragma unroll
  for (int it = 0; it < 4; ++it) {
    mcr[it] = mc[base + it * 256];
    mrr[it] = mr[base + it * 256];
  }

  float a0[8], a1[8];
#pragma unroll
  for (int q = 0; q < 8; ++q) { a0[q] = 0.f; a1[q] = 0.f; }

#pragma unroll
  for (int q = 0; q < 8; ++q) {
    const f32x4* xb = (const f32x4*)x + (size_t)(bg * 8 + q) * 196608;
    float s0 = 0.f, s1 = 0.f;
#pragma unroll
    for (int it = 0; it < 4; ++it) {
      int i = base + it * 256;
      f32x4 x0 = __builtin_nontemporal_load(xb + i);
      f32x4 x1 = __builtin_nontemporal_load(xb + i + 65536);
      f32x4 x2 = __builtin_nontemporal_load(xb + i + 131072);
      f32x4 sv = x0 + x1 + x2;
      f32x4 m0 = mcr[it], m1 = mrr[it];
      s0 += sv.x * m0.x + sv.y * m0.y + sv.z * m0.z + sv.w * m0.w;
      s1 += sv.x * m1.x + sv.y * m1.y + sv.z * m1.z + sv.w * m1.w;
    }
    a0[q] = s0; a1[q] = s1;
  }

  // in-block reduce: wave shuffle, then cross-wave via LDS
  int lane = tid & 63, wv = tid >> 6;
  __shared__ float red[4][16];
#pragma unroll
  for (int q = 0; q < 8; ++q) {
    float v0 = a0[q], v1 = a1[q];
#pragma unroll
    for (int off = 32; off > 0; off >>= 1) {
      v0 += __shfl_down(v0, off);
      v1 += __shfl_down(v1, off);
    }
    if (lane == 0) { red[wv][q * 2] = v0; red[wv][q * 2 + 1] = v1; }
  }
  __syncthreads();
  if (tid < 16) {
    float s = red[0][tid] + red[1][tid] + red[2][tid] + red[3][tid];
    int q = tid >> 1, o = tid & 1;
    int b = bg * 8 + q;
    partial[(b * 64 + sub) * 2 + o] = s;
  }
  __threadfence();
  __syncthreads();
  __shared__ int lastf;
  if (tid == 0) lastf = (atomicAdd(counter, 1) == KC_BLOCKS - 1);
  __syncthreads();
  if (lastf) {
    __threadfence();
    if (tid < 128) {
      int b = tid >> 1, o = tid & 1;
      float s = 0.f;
      for (int sb = 0; sb < 64; ++sb) s += partial[(b * 64 + sb) * 2 + o];
      out[b * 2 + o] = 1.0f / (1.0f + expf(-s));
    }
  }
}

extern "C" void kernel_launch(void* const* d_in, const int* in_sizes, int n_in,
                              void* d_out, int out_size, void* d_ws, size_t ws_size,
                              hipStream_t stream) {
  const float* x   = (const float*)d_in[0];   // [64,3,512,512]
  const float* att = (const float*)d_in[1];   // [512,512]
  const float* rw  = (const float*)d_in[2];   // [512]
  const float* cw  = (const float*)d_in[3];   // [512]
  float* out = (float*)d_out;                 // [64,2]

  // workspace layout (~3.6 MiB)
  unsigned short* DT  = (unsigned short*)d_ws;        // 512 KB
  unsigned short* Arw = DT + HWTOT;                   // 512 KB
  unsigned short* Acw = Arw + HWTOT;                  // 512 KB
  float* Mrow    = (float*)(Acw + HWTOT);             // 1 MB
  float* Mcol    = Mrow + HWTOT;                      // 1 MB
  float* partial = Mcol + HWTOT;                      // 32 KB
  int*   counter = (int*)(partial + 8192);

  k0_prep<<<1024, 256, 0, stream>>>(att, rw, cw, DT, Arw, Acw, counter);
  kM<<<32, 256, 0, stream>>>(DT, Arw, Acw, Mrow, Mcol);
  kc_dot<<<KC_BLOCKS, 256, 0, stream>>>(x, Mcol, Mrow, partial, counter, out);
}

// Round 3
// 163.889 us; speedup vs baseline: 1.0311x; 1.0311x over previous
//
#include <hip/hip_runtime.h>
#include <hip/hip_bf16.h>
#include <math.h>

// B=64, C=3, H=W=512.
// out[b,0] = sigmoid( sum_{c,h,w} x[b,c,h,w] * M_col[h,w] / C )
// out[b,1] = sigmoid( sum_{c,h,w} x[b,c,h,w] * M_row[h,w] / C )
// M_row = (1/HW) D^T (diag(rw) A) D ;  M_col = (1/HW) D^T (A diag(cw)) D
// D = orthonormal DCT-II matrix, DT[n][k] = D[k][n].

typedef __attribute__((ext_vector_type(8))) short bf16x8;
typedef __attribute__((ext_vector_type(4))) float f32x4;

#define NFULL 512
#define HWTOT 262144
#define SCALE_M (1.0f / 786432.0f)      // 1/(H*W*C)
#define KC_BLOCKS 2048

static __device__ __forceinline__ unsigned short f_to_bf16(float f) {
  union { float f; unsigned int i; } v; v.f = f;
  unsigned int r = v.i + 0x7FFFu + ((v.i >> 16) & 1u);   // round-nearest-even
  return (unsigned short)(r >> 16);
}

// ---------------- K0: trig table + scaled bf16 casts + counter reset ----------------
// DT[r][c] = s_c * cos(pi*(r+0.5)*c/512) = D[c][r]
// Arw[r][c] = A[r,c]*rw[r] ; Acw[r][c] = A[r,c]*cw[c]   (A indexed [freq_k, freq_l])
__global__ void k0_prep(const float* __restrict__ att,
                        const float* __restrict__ rw,
                        const float* __restrict__ cw,
                        unsigned short* __restrict__ DT,
                        unsigned short* __restrict__ Arw,
                        unsigned short* __restrict__ Acw,
                        int* __restrict__ counter) {
  int idx = blockIdx.x * blockDim.x + threadIdx.x;   // 0..262143
  int r = idx >> 9;
  int c = idx & 511;
  unsigned int ph = ((unsigned int)(2 * r + 1) * (unsigned int)c) & 2047u;  // period 2048
  float s = (c == 0) ? 0.04419417382415922f   // sqrt(1/512)
                     : 0.0625f;               // sqrt(2/512)
  DT[idx] = f_to_bf16(s * cospif((float)ph * (1.0f / 1024.0f)));
  float a = att[idx];
  Arw[idx] = f_to_bf16(a * rw[r]);
  Acw[idx] = f_to_bf16(a * cw[c]);
  if (idx == 0) *counter = 0;
}

// ---------------- KA: T1 = Arw@D, T2 = Acw@D ; store transposed bf16 ----------------
// One wave per 16x16 tile of both outputs; B fragment (DT rows) shared.
// T1T[w][k] = T1[k][w], T2T[w][k] = T2[k][w]
__global__ void ka_gemm(const unsigned short* __restrict__ DT,
                        const unsigned short* __restrict__ Arw,
                        const unsigned short* __restrict__ Acw,
                        unsigned short* __restrict__ T1T,
                        unsigned short* __restrict__ T2T) {
  int wave = (blockIdx.x * blockDim.x + threadIdx.x) >> 6;   // 0..1023
  int lane = threadIdx.x & 63;
  int tk = wave >> 5, tw = wave & 31;
  int row_a = tk * 16 + (lane & 15);     // k-row of A'
  int row_b = tw * 16 + (lane & 15);     // w-row of DT (= output col)
  int koff = (lane >> 4) * 8;

  const bf16x8* A1 = (const bf16x8*)(Arw + row_a * NFULL);
  const bf16x8* A2 = (const bf16x8*)(Acw + row_a * NFULL);
  const bf16x8* Bp = (const bf16x8*)(DT  + row_b * NFULL);

  f32x4 acc1 = {0.f, 0.f, 0.f, 0.f};
  f32x4 acc2 = {0.f, 0.f, 0.f, 0.f};
#pragma unroll 4
  for (int l0 = 0; l0 < NFULL; l0 += 32) {
    int e = (l0 + koff) >> 3;
    bf16x8 b = Bp[e];
    acc1 = __builtin_amdgcn_mfma_f32_16x16x32_bf16(A1[e], b, acc1, 0, 0, 0);
    acc2 = __builtin_amdgcn_mfma_f32_16x16x32_bf16(A2[e], b, acc2, 0, 0, 0);
  }
  // C/D layout: col = lane&15, row = (lane>>4)*4 + j  -> store transposed
  int col = lane & 15, r0 = (lane >> 4) * 4;
  int w  = tw * 16 + col;
  int k0 = tk * 16 + r0;
  unsigned int g0 = f_to_bf16(acc1[0]) | ((unsigned int)f_to_bf16(acc1[1]) << 16);
  unsigned int g1 = f_to_bf16(acc1[2]) | ((unsigned int)f_to_bf16(acc1[3]) << 16);
  unsigned int c0 = f_to_bf16(acc2[0]) | ((unsigned int)f_to_bf16(acc2[1]) << 16);
  unsigned int c1 = f_to_bf16(acc2[2]) | ((unsigned int)f_to_bf16(acc2[3]) << 16);
  *(uint2*)(T1T + w * NFULL + k0) = make_uint2(g0, g1);
  *(uint2*)(T2T + w * NFULL + k0) = make_uint2(c0, c1);
}

// ---------------- KB: M_row = D^T @ T1, M_col = D^T @ T2 (fp32 out, scaled) ----------------
__global__ void kb_gemm(const unsigned short* __restrict__ DT,
                        const unsigned short* __restrict__ T1T,
                        const unsigned short* __restrict__ T2T,
                        float* __restrict__ Mrow,
                        float* __restrict__ Mcol) {
  int wave = (blockIdx.x * blockDim.x + threadIdx.x) >> 6;
  int lane = threadIdx.x & 63;
  int th = wave >> 5, tw = wave & 31;
  int row_a = th * 16 + (lane & 15);     // h-row of D^T
  int row_b = tw * 16 + (lane & 15);     // w-row of T^T
  int koff = (lane >> 4) * 8;

  const bf16x8* Ap = (const bf16x8*)(DT  + row_a * NFULL);
  const bf16x8* Rp = (const bf16x8*)(T1T + row_b * NFULL);
  const bf16x8* Cp = (const bf16x8*)(T2T + row_b * NFULL);

  f32x4 accR = {0.f, 0.f, 0.f, 0.f};
  f32x4 accC = {0.f, 0.f, 0.f, 0.f};
#pragma unroll 4
  for (int k0 = 0; k0 < NFULL; k0 += 32) {
    int e = (k0 + koff) >> 3;
    bf16x8 a = Ap[e];
    accR = __builtin_amdgcn_mfma_f32_16x16x32_bf16(a, Rp[e], accR, 0, 0, 0);
    accC = __builtin_amdgcn_mfma_f32_16x16x32_bf16(a, Cp[e], accC, 0, 0, 0);
  }
  int col = lane & 15, r0 = (lane >> 4) * 4;
  int h0 = th * 16 + r0;
  int w  = tw * 16 + col;
#pragma unroll
  for (int j = 0; j < 4; ++j) {
    Mrow[(h0 + j) * NFULL + w] = accR[j] * SCALE_M;
    Mcol[(h0 + j) * NFULL + w] = accC[j] * SCALE_M;
  }
}

// ---------------- KC: stream x once (nt loads), fused dot + final reduce + sigmoid ----
// grid = 64 batches x 32 hw-slices; full occupancy. M reads hit L2 (2 MB resident).
__global__ void kc_dot(const float* __restrict__ x,
                       const float* __restrict__ Mcol,
                       const float* __restrict__ Mrow,
                       float* __restrict__ partial,
                       int* __restrict__ counter,
                       float* __restrict__ out) {
  int b   = blockIdx.x >> 5;
  int sub = blockIdx.x & 31;
  int tid = threadIdx.x;
  const f32x4* xb = (const f32x4*)x + (size_t)b * 196608;   // 3*65536 float4
  const f32x4* mc = (const f32x4*)Mcol;
  const f32x4* mr = (const f32x4*)Mrow;

  float a0 = 0.f, a1 = 0.f;
  int base = sub * 2048 + tid;
#pragma unroll
  for (int it = 0; it < 8; ++it) {
    int i = base + it * 256;            // hw float4 index, 0..65535
    f32x4 x0 = __builtin_nontemporal_load(xb + i);
    f32x4 x1 = __builtin_nontemporal_load(xb + i + 65536);
    f32x4 x2 = __builtin_nontemporal_load(xb + i + 131072);
    f32x4 m0 = mc[i];
    f32x4 m1 = mr[i];
    f32x4 sv = x0 + x1 + x2;
    a0 += sv.x * m0.x + sv.y * m0.y + sv.z * m0.z + sv.w * m0.w;
    a1 += sv.x * m1.x + sv.y * m1.y + sv.z * m1.z + sv.w * m1.w;
  }

  // wave shuffle reduce, then cross-wave via LDS
  int lane = tid & 63, wv = tid >> 6;
#pragma unroll
  for (int off = 32; off > 0; off >>= 1) {
    a0 += __shfl_down(a0, off);
    a1 += __shfl_down(a1, off);
  }
  __shared__ float red[8];
  if (lane == 0) { red[wv * 2] = a0; red[wv * 2 + 1] = a1; }
  __syncthreads();
  if (tid == 0) {
    float s0 = red[0] + red[2] + red[4] + red[6];
    float s1 = red[1] + red[3] + red[5] + red[7];
    partial[(b * 32 + sub) * 2 + 0] = s0;
    partial[(b * 32 + sub) * 2 + 1] = s1;
    __threadfence();
  }
  __syncthreads();
  __shared__ int lastf;
  if (tid == 0) lastf = (atomicAdd(counter, 1) == KC_BLOCKS - 1);
  __syncthreads();
  if (lastf) {
    __threadfence();
    if (tid < 128) {
      int bb = tid >> 1, o = tid & 1;
      float s = 0.f;
      for (int sb = 0; sb < 32; ++sb) s += partial[(bb * 32 + sb) * 2 + o];
      out[bb * 2 + o] = 1.0f / (1.0f + expf(-s));
    }
  }
}

extern "C" void kernel_launch(void* const* d_in, const int* in_sizes, int n_in,
                              void* d_out, int out_size, void* d_ws, size_t ws_size,
                              hipStream_t stream) {
  const float* x   = (const float*)d_in[0];   // [64,3,512,512]
  const float* att = (const float*)d_in[1];   // [512,512]
  const float* rw  = (const float*)d_in[2];   // [512]
  const float* cw  = (const float*)d_in[3];   // [512]
  float* out = (float*)d_out;                 // [64,2]

  // workspace layout (~4.6 MiB)
  unsigned short* DT  = (unsigned short*)d_ws;        // 512 KB
  unsigned short* Arw = DT  + HWTOT;                  // 512 KB
  unsigned short* Acw = Arw + HWTOT;                  // 512 KB
  unsigned short* T1T = Acw + HWTOT;                  // 512 KB
  unsigned short* T2T = T1T + HWTOT;                  // 512 KB
  float* Mrow    = (float*)(T2T + HWTOT);             // 1 MB
  float* Mcol    = Mrow + HWTOT;                      // 1 MB
  float* partial = Mcol + HWTOT;                      // 16 KB
  int*   counter = (int*)(partial + 4096);

  k0_prep<<<1024, 256, 0, stream>>>(att, rw, cw, DT, Arw, Acw, counter);
  ka_gemm<<<256, 256, 0, stream>>>(DT, Arw, Acw, T1T, T2T);
  kb_gemm<<<256, 256, 0, stream>>>(DT, T1T, T2T, Mrow, Mcol);
  kc_dot<<<KC_BLOCKS, 256, 0, stream>>>(x, Mcol, Mrow, partial, counter, out);
}

// Round 4
// 122.606 us; speedup vs baseline: 1.3783x; 1.3367x over previous
//
#include <hip/hip_runtime.h>
#include <hip/hip_bf16.h>
#include <math.h>

// B=64, C=3, H=W=512.
// out[b,0] = sigmoid( sum_{c,h,w} x[b,c,h,w] * M_col[h,w] / C )
// out[b,1] = sigmoid( sum_{c,h,w} x[b,c,h,w] * M_row[h,w] / C )
// M_row = (1/HW) D^T (diag(rw) A) D ;  M_col = (1/HW) D^T (A diag(cw)) D
// D = orthonormal DCT-II matrix, DT[n][k] = D[k][n].

typedef __attribute__((ext_vector_type(8))) short bf16x8;
typedef __attribute__((ext_vector_type(4))) float f32x4;

#define NFULL 512
#define HWTOT 262144
#define SCALE_M (1.0f / 786432.0f)      // 1/(H*W*C)
#define KC_BLOCKS 2048

static __device__ __forceinline__ unsigned short f_to_bf16(float f) {
  union { float f; unsigned int i; } v; v.f = f;
  unsigned int r = v.i + 0x7FFFu + ((v.i >> 16) & 1u);   // round-nearest-even
  return (unsigned short)(r >> 16);
}

// ---------------- K0: trig table + scaled bf16 casts + counter reset ----------------
// DT[r][c] = s_c * cos(pi*(r+0.5)*c/512) = D[c][r]
// Arw[r][c] = A[r,c]*rw[r] ; Acw[r][c] = A[r,c]*cw[c]
__global__ void k0_prep(const float* __restrict__ att,
                        const float* __restrict__ rw,
                        const float* __restrict__ cw,
                        unsigned short* __restrict__ DT,
                        unsigned short* __restrict__ Arw,
                        unsigned short* __restrict__ Acw,
                        int* __restrict__ counter) {
  int idx = blockIdx.x * blockDim.x + threadIdx.x;   // 0..262143
  int r = idx >> 9;
  int c = idx & 511;
  unsigned int ph = ((unsigned int)(2 * r + 1) * (unsigned int)c) & 2047u;  // period 2048
  float s = (c == 0) ? 0.04419417382415922f   // sqrt(1/512)
                     : 0.0625f;               // sqrt(2/512)
  DT[idx] = f_to_bf16(s * cospif((float)ph * (1.0f / 1024.0f)));
  float a = att[idx];
  Arw[idx] = f_to_bf16(a * rw[r]);
  Acw[idx] = f_to_bf16(a * cw[c]);
  if (idx == 0) *counter = 0;
}

// ---------------- KA: T1 = Arw@D, T2 = Acw@D ; store transposed bf16 ----------------
__global__ void ka_gemm(const unsigned short* __restrict__ DT,
                        const unsigned short* __restrict__ Arw,
                        const unsigned short* __restrict__ Acw,
                        unsigned short* __restrict__ T1T,
                        unsigned short* __restrict__ T2T) {
  int wave = (blockIdx.x * blockDim.x + threadIdx.x) >> 6;   // 0..1023
  int lane = threadIdx.x & 63;
  int tk = wave >> 5, tw = wave & 31;
  int row_a = tk * 16 + (lane & 15);
  int row_b = tw * 16 + (lane & 15);
  int koff = (lane >> 4) * 8;

  const bf16x8* A1 = (const bf16x8*)(Arw + row_a * NFULL);
  const bf16x8* A2 = (const bf16x8*)(Acw + row_a * NFULL);
  const bf16x8* Bp = (const bf16x8*)(DT  + row_b * NFULL);

  f32x4 acc1 = {0.f, 0.f, 0.f, 0.f};
  f32x4 acc2 = {0.f, 0.f, 0.f, 0.f};
#pragma unroll 4
  for (int l0 = 0; l0 < NFULL; l0 += 32) {
    int e = (l0 + koff) >> 3;
    bf16x8 b = Bp[e];
    acc1 = __builtin_amdgcn_mfma_f32_16x16x32_bf16(A1[e], b, acc1, 0, 0, 0);
    acc2 = __builtin_amdgcn_mfma_f32_16x16x32_bf16(A2[e], b, acc2, 0, 0, 0);
  }
  int col = lane & 15, r0 = (lane >> 4) * 4;
  int w  = tw * 16 + col;
  int k0 = tk * 16 + r0;
  unsigned int g0 = f_to_bf16(acc1[0]) | ((unsigned int)f_to_bf16(acc1[1]) << 16);
  unsigned int g1 = f_to_bf16(acc1[2]) | ((unsigned int)f_to_bf16(acc1[3]) << 16);
  unsigned int c0 = f_to_bf16(acc2[0]) | ((unsigned int)f_to_bf16(acc2[1]) << 16);
  unsigned int c1 = f_to_bf16(acc2[2]) | ((unsigned int)f_to_bf16(acc2[3]) << 16);
  *(uint2*)(T1T + w * NFULL + k0) = make_uint2(g0, g1);
  *(uint2*)(T2T + w * NFULL + k0) = make_uint2(c0, c1);
}

// ---------------- KB: M_row = D^T @ T1, M_col = D^T @ T2 (fp32 out, scaled) ----------------
__global__ void kb_gemm(const unsigned short* __restrict__ DT,
                        const unsigned short* __restrict__ T1T,
                        const unsigned short* __restrict__ T2T,
                        float* __restrict__ Mrow,
                        float* __restrict__ Mcol) {
  int wave = (blockIdx.x * blockDim.x + threadIdx.x) >> 6;
  int lane = threadIdx.x & 63;
  int th = wave >> 5, tw = wave & 31;
  int row_a = th * 16 + (lane & 15);
  int row_b = tw * 16 + (lane & 15);
  int koff = (lane >> 4) * 8;

  const bf16x8* Ap = (const bf16x8*)(DT  + row_a * NFULL);
  const bf16x8* Rp = (const bf16x8*)(T1T + row_b * NFULL);
  const bf16x8* Cp = (const bf16x8*)(T2T + row_b * NFULL);

  f32x4 accR = {0.f, 0.f, 0.f, 0.f};
  f32x4 accC = {0.f, 0.f, 0.f, 0.f};
#pragma unroll 4
  for (int k0 = 0; k0 < NFULL; k0 += 32) {
    int e = (k0 + koff) >> 3;
    bf16x8 a = Ap[e];
    accR = __builtin_amdgcn_mfma_f32_16x16x32_bf16(a, Rp[e], accR, 0, 0, 0);
    accC = __builtin_amdgcn_mfma_f32_16x16x32_bf16(a, Cp[e], accC, 0, 0, 0);
  }
  int col = lane & 15, r0 = (lane >> 4) * 4;
  int h0 = th * 16 + r0;
  int w  = tw * 16 + col;
#pragma unroll
  for (int j = 0; j < 4; ++j) {
    Mrow[(h0 + j) * NFULL + w] = accR[j] * SCALE_M;
    Mcol[(h0 + j) * NFULL + w] = accC[j] * SCALE_M;
  }
}

// ---------------- KC: stream x once (cached loads), fused dot + reduce + sigmoid ----
// grid = 64 batches x 32 hw-slices; ~32 waves/CU. M (2 MB) rides L2/L3.
__global__ void kc_dot(const float* __restrict__ x,
                       const float* __restrict__ Mcol,
                       const float* __restrict__ Mrow,
                       float* __restrict__ partial,
                       int* __restrict__ counter,
                       float* __restrict__ out) {
  int b   = blockIdx.x >> 5;
  int sub = blockIdx.x & 31;
  int tid = threadIdx.x;
  const f32x4* xb = (const f32x4*)x + (size_t)b * 196608;   // 3*65536 float4
  const f32x4* mc = (const f32x4*)Mcol;
  const f32x4* mr = (const f32x4*)Mrow;

  float a0 = 0.f, a1 = 0.f;
  int base = sub * 2048 + tid;
#pragma unroll
  for (int it = 0; it < 8; ++it) {
    int i = base + it * 256;            // hw float4 index, 0..65535
    f32x4 m0 = mc[i];
    f32x4 m1 = mr[i];
    f32x4 x0 = xb[i];
    f32x4 x1 = xb[i + 65536];
    f32x4 x2 = xb[i + 131072];
    f32x4 sv = x0 + x1 + x2;
    a0 += sv.x * m0.x + sv.y * m0.y + sv.z * m0.z + sv.w * m0.w;
    a1 += sv.x * m1.x + sv.y * m1.y + sv.z * m1.z + sv.w * m1.w;
  }

  // wave shuffle reduce, then cross-wave via LDS
  int lane = tid & 63, wv = tid >> 6;
#pragma unroll
  for (int off = 32; off > 0; off >>= 1) {
    a0 += __shfl_down(a0, off);
    a1 += __shfl_down(a1, off);
  }
  __shared__ float red[8];
  if (lane == 0) { red[wv * 2] = a0; red[wv * 2 + 1] = a1; }
  __syncthreads();
  if (tid == 0) {
    float s0 = red[0] + red[2] + red[4] + red[6];
    float s1 = red[1] + red[3] + red[5] + red[7];
    partial[(b * 32 + sub) * 2 + 0] = s0;
    partial[(b * 32 + sub) * 2 + 1] = s1;
    __threadfence();
  }
  __syncthreads();
  __shared__ int lastf;
  if (tid == 0) lastf = (atomicAdd(counter, 1) == KC_BLOCKS - 1);
  __syncthreads();
  if (lastf) {
    __threadfence();
    if (tid < 128) {
      int bb = tid >> 1, o = tid & 1;
      float s = 0.f;
      for (int sb = 0; sb < 32; ++sb) s += partial[(bb * 32 + sb) * 2 + o];
      out[bb * 2 + o] = 1.0f / (1.0f + expf(-s));
    }
  }
}

extern "C" void kernel_launch(void* const* d_in, const int* in_sizes, int n_in,
                              void* d_out, int out_size, void* d_ws, size_t ws_size,
                              hipStream_t stream) {
  const float* x   = (const float*)d_in[0];   // [64,3,512,512]
  const float* att = (const float*)d_in[1];   // [512,512]
  const float* rw  = (const float*)d_in[2];   // [512]
  const float* cw  = (const float*)d_in[3];   // [512]
  float* out = (float*)d_out;                 // [64,2]

  // workspace layout (~4.6 MiB)
  unsigned short* DT  = (unsigned short*)d_ws;        // 512 KB
  unsigned short* Arw = DT  + HWTOT;                  // 512 KB
  unsigned short* Acw = Arw + HWTOT;                  // 512 KB
  unsigned short* T1T = Acw + HWTOT;                  // 512 KB
  unsigned short* T2T = T1T + HWTOT;                  // 512 KB
  float* Mrow    = (float*)(T2T + HWTOT);             // 1 MB
  float* Mcol    = Mrow + HWTOT;                      // 1 MB
  float* partial = Mcol + HWTOT;                      // 16 KB
  int*   counter = (int*)(partial + 4096);

  k0_prep<<<1024, 256, 0, stream>>>(att, rw, cw, DT, Arw, Acw, counter);
  ka_gemm<<<256, 256, 0, stream>>>(DT, Arw, Acw, T1T, T2T);
  kb_gemm<<<256, 256, 0, stream>>>(DT, T1T, T2T, Mrow, Mcol);
  kc_dot<<<KC_BLOCKS, 256, 0, stream>>>(x, Mcol, Mrow, partial, counter, out);
}

// Round 5
// 57.992 us; speedup vs baseline: 2.9140x; 2.1142x over previous
//
#include <hip/hip_runtime.h>
#include <hip/hip_bf16.h>
#include <math.h>

// B=64, C=3, H=W=512.
// out[b,0] = sigmoid( sum_{c,h,w} x[b,c,h,w] * M_col[h,w] / C )
// out[b,1] = sigmoid( sum_{c,h,w} x[b,c,h,w] * M_row[h,w] / C )
// M_row = (1/HW) D^T (diag(rw) A) D ;  M_col = (1/HW) D^T (A diag(cw)) D
// D = orthonormal DCT-II matrix, DT[n][k] = D[k][n].

typedef __attribute__((ext_vector_type(8))) short bf16x8;
typedef __attribute__((ext_vector_type(4))) float f32x4;

#define NFULL 512
#define HWTOT 262144
#define SCALE_M (1.0f / 786432.0f)      // 1/(H*W*C)
#define KC_BLOCKS 2048

static __device__ __forceinline__ unsigned short f_to_bf16(float f) {
  union { float f; unsigned int i; } v; v.f = f;
  unsigned int r = v.i + 0x7FFFu + ((v.i >> 16) & 1u);   // round-nearest-even
  return (unsigned short)(r >> 16);
}

// ---------------- K0: trig table + scaled bf16 casts ----------------
// DT[r][c] = s_c * cos(pi*(r+0.5)*c/512) = D[c][r]
// Arw[r][c] = A[r,c]*rw[r] ; Acw[r][c] = A[r,c]*cw[c]
__global__ void k0_prep(const float* __restrict__ att,
                        const float* __restrict__ rw,
                        const float* __restrict__ cw,
                        unsigned short* __restrict__ DT,
                        unsigned short* __restrict__ Arw,
                        unsigned short* __restrict__ Acw) {
  int idx = blockIdx.x * blockDim.x + threadIdx.x;   // 0..262143
  int r = idx >> 9;
  int c = idx & 511;
  unsigned int ph = ((unsigned int)(2 * r + 1) * (unsigned int)c) & 2047u;  // period 2048
  float s = (c == 0) ? 0.04419417382415922f   // sqrt(1/512)
                     : 0.0625f;               // sqrt(2/512)
  DT[idx] = f_to_bf16(s * cospif((float)ph * (1.0f / 1024.0f)));
  float a = att[idx];
  Arw[idx] = f_to_bf16(a * rw[r]);
  Acw[idx] = f_to_bf16(a * cw[c]);
}

// ---------------- KA: T1 = Arw@D, T2 = Acw@D ; store transposed bf16 ----------------
__global__ void ka_gemm(const unsigned short* __restrict__ DT,
                        const unsigned short* __restrict__ Arw,
                        const unsigned short* __restrict__ Acw,
                        unsigned short* __restrict__ T1T,
                        unsigned short* __restrict__ T2T) {
  int wave = (blockIdx.x * blockDim.x + threadIdx.x) >> 6;   // 0..1023
  int lane = threadIdx.x & 63;
  int tk = wave >> 5, tw = wave & 31;
  int row_a = tk * 16 + (lane & 15);
  int row_b = tw * 16 + (lane & 15);
  int koff = (lane >> 4) * 8;

  const bf16x8* A1 = (const bf16x8*)(Arw + row_a * NFULL);
  const bf16x8* A2 = (const bf16x8*)(Acw + row_a * NFULL);
  const bf16x8* Bp = (const bf16x8*)(DT  + row_b * NFULL);

  f32x4 acc1 = {0.f, 0.f, 0.f, 0.f};
  f32x4 acc2 = {0.f, 0.f, 0.f, 0.f};
#pragma unroll 4
  for (int l0 = 0; l0 < NFULL; l0 += 32) {
    int e = (l0 + koff) >> 3;
    bf16x8 b = Bp[e];
    acc1 = __builtin_amdgcn_mfma_f32_16x16x32_bf16(A1[e], b, acc1, 0, 0, 0);
    acc2 = __builtin_amdgcn_mfma_f32_16x16x32_bf16(A2[e], b, acc2, 0, 0, 0);
  }
  int col = lane & 15, r0 = (lane >> 4) * 4;
  int w  = tw * 16 + col;
  int k0 = tk * 16 + r0;
  unsigned int g0 = f_to_bf16(acc1[0]) | ((unsigned int)f_to_bf16(acc1[1]) << 16);
  unsigned int g1 = f_to_bf16(acc1[2]) | ((unsigned int)f_to_bf16(acc1[3]) << 16);
  unsigned int c0 = f_to_bf16(acc2[0]) | ((unsigned int)f_to_bf16(acc2[1]) << 16);
  unsigned int c1 = f_to_bf16(acc2[2]) | ((unsigned int)f_to_bf16(acc2[3]) << 16);
  *(uint2*)(T1T + w * NFULL + k0) = make_uint2(g0, g1);
  *(uint2*)(T2T + w * NFULL + k0) = make_uint2(c0, c1);
}

// ---------------- KB: M_row = D^T @ T1, M_col = D^T @ T2 (fp32 out, scaled) ----------------
__global__ void kb_gemm(const unsigned short* __restrict__ DT,
                        const unsigned short* __restrict__ T1T,
                        const unsigned short* __restrict__ T2T,
                        float* __restrict__ Mrow,
                        float* __restrict__ Mcol) {
  int wave = (blockIdx.x * blockDim.x + threadIdx.x) >> 6;
  int lane = threadIdx.x & 63;
  int th = wave >> 5, tw = wave & 31;
  int row_a = th * 16 + (lane & 15);
  int row_b = tw * 16 + (lane & 15);
  int koff = (lane >> 4) * 8;

  const bf16x8* Ap = (const bf16x8*)(DT  + row_a * NFULL);
  const bf16x8* Rp = (const bf16x8*)(T1T + row_b * NFULL);
  const bf16x8* Cp = (const bf16x8*)(T2T + row_b * NFULL);

  f32x4 accR = {0.f, 0.f, 0.f, 0.f};
  f32x4 accC = {0.f, 0.f, 0.f, 0.f};
#pragma unroll 4
  for (int k0 = 0; k0 < NFULL; k0 += 32) {
    int e = (k0 + koff) >> 3;
    bf16x8 a = Ap[e];
    accR = __builtin_amdgcn_mfma_f32_16x16x32_bf16(a, Rp[e], accR, 0, 0, 0);
    accC = __builtin_amdgcn_mfma_f32_16x16x32_bf16(a, Cp[e], accC, 0, 0, 0);
  }
  int col = lane & 15, r0 = (lane >> 4) * 4;
  int h0 = th * 16 + r0;
  int w  = tw * 16 + col;
#pragma unroll
  for (int j = 0; j < 4; ++j) {
    Mrow[(h0 + j) * NFULL + w] = accR[j] * SCALE_M;
    Mcol[(h0 + j) * NFULL + w] = accC[j] * SCALE_M;
  }
}

// ---------------- KC: stream x once (cached loads), write per-block partials ----
// grid = 64 batches x 32 hw-slices; ~32 waves/CU. M (2 MB) rides L2/L3.
// NO atomics / fences: same-address device atomics from 2048 blocks serialize
// (~100+ us tail, measured R3/R4).
__global__ void kc_dot(const float* __restrict__ x,
                       const float* __restrict__ Mcol,
                       const float* __restrict__ Mrow,
                       float* __restrict__ partial) {
  int b   = blockIdx.x >> 5;
  int sub = blockIdx.x & 31;
  int tid = threadIdx.x;
  const f32x4* xb = (const f32x4*)x + (size_t)b * 196608;   // 3*65536 float4
  const f32x4* mc = (const f32x4*)Mcol;
  const f32x4* mr = (const f32x4*)Mrow;

  float a0 = 0.f, a1 = 0.f;
  int base = sub * 2048 + tid;
#pragma unroll
  for (int it = 0; it < 8; ++it) {
    int i = base + it * 256;            // hw float4 index, 0..65535
    f32x4 x0 = xb[i];
    f32x4 x1 = xb[i + 65536];
    f32x4 x2 = xb[i + 131072];
    f32x4 m0 = mc[i];
    f32x4 m1 = mr[i];
    f32x4 sv = x0 + x1 + x2;
    a0 += sv.x * m0.x + sv.y * m0.y + sv.z * m0.z + sv.w * m0.w;
    a1 += sv.x * m1.x + sv.y * m1.y + sv.z * m1.z + sv.w * m1.w;
  }

  // wave shuffle reduce, then cross-wave via LDS
  int lane = tid & 63, wv = tid >> 6;
#pragma unroll
  for (int off = 32; off > 0; off >>= 1) {
    a0 += __shfl_down(a0, off);
    a1 += __shfl_down(a1, off);
  }
  __shared__ float red[8];
  if (lane == 0) { red[wv * 2] = a0; red[wv * 2 + 1] = a1; }
  __syncthreads();
  if (tid == 0) {
    float s0 = red[0] + red[2] + red[4] + red[6];
    float s1 = red[1] + red[3] + red[5] + red[7];
    partial[(b * 32 + sub) * 2 + 0] = s0;
    partial[(b * 32 + sub) * 2 + 1] = s1;
  }
}

// ---------------- KD: final deterministic reduce + sigmoid ----------------
__global__ void kd_final(const float* __restrict__ partial, float* __restrict__ out) {
  int t = threadIdx.x;           // 0..127 -> (b, o)
  int b = t >> 1, o = t & 1;
  float s = 0.f;
#pragma unroll
  for (int j = 0; j < 32; ++j) s += partial[(b * 32 + j) * 2 + o];
  out[b * 2 + o] = 1.0f / (1.0f + expf(-s));
}

extern "C" void kernel_launch(void* const* d_in, const int* in_sizes, int n_in,
                              void* d_out, int out_size, void* d_ws, size_t ws_size,
                              hipStream_t stream) {
  const float* x   = (const float*)d_in[0];   // [64,3,512,512]
  const float* att = (const float*)d_in[1];   // [512,512]
  const float* rw  = (const float*)d_in[2];   // [512]
  const float* cw  = (const float*)d_in[3];   // [512]
  float* out = (float*)d_out;                 // [64,2]

  // workspace layout (~4.6 MiB)
  unsigned short* DT  = (unsigned short*)d_ws;        // 512 KB
  unsigned short* Arw = DT  + HWTOT;                  // 512 KB
  unsigned short* Acw = Arw + HWTOT;                  // 512 KB
  unsigned short* T1T = Acw + HWTOT;                  // 512 KB
  unsigned short* T2T = T1T + HWTOT;                  // 512 KB
  float* Mrow    = (float*)(T2T + HWTOT);             // 1 MB
  float* Mcol    = Mrow + HWTOT;                      // 1 MB
  float* partial = Mcol + HWTOT;                      // 16 KB

  k0_prep<<<1024, 256, 0, stream>>>(att, rw, cw, DT, Arw, Acw);
  ka_gemm<<<256, 256, 0, stream>>>(DT, Arw, Acw, T1T, T2T);
  kb_gemm<<<256, 256, 0, stream>>>(DT, T1T, T2T, Mrow, Mcol);
  kc_dot<<<KC_BLOCKS, 256, 0, stream>>>(x, Mcol, Mrow, partial);
  kd_final<<<1, 128, 0, stream>>>(partial, out);
}